// Round 1
// baseline (1251.678 us; speedup 1.0000x reference)
//
#include <hip/hip_runtime.h>
#include <math.h>

// Problem constants (fixed by the reference).
#define B_   16
#define C_   256
#define N_   16384
#define K_   64
#define CO_  512

// ---------------------------------------------------------------------------
// K1: fused  l2norm(x, axis=C) -> logits -> softmax(K) -> aggregation
//   agg[b,k,c]  = sum_n a[b,k,n] * xn[b,c,n]   (a' = a * rnorm folded, raw x used)
//   asum[b,k]   = sum_n a[b,k,n]
// Grid: 256 blocks (16 tiles per batch), 512 threads (8 waves). Each block
// owns 1024 columns, processed in 32-column chunks.
// ---------------------------------------------------------------------------
__global__ __launch_bounds__(512, 4) void k1_assign_agg(
    const float* __restrict__ x,
    const float* __restrict__ aw,
    const float* __restrict__ ab,
    float* __restrict__ agg,
    float* __restrict__ asum)
{
    __shared__ float xA[32][36];     // [j][c'] phase-A x block (stride 36: f4-aligned, bank-spread)
    __shared__ float wA[64][36];     // [k][c'] assignment-weight block
    __shared__ float xB[128][33];    // [c'][j] phase-B x block
    __shared__ float lgs[64][36];    // a' = softmax * rnorm, [k][j]
    __shared__ float colsq[16][33];  // per-column sumsq partials
    __shared__ float rnorm_s[32];
    __shared__ float awred[8][64];

    const int t    = threadIdx.x;
    const int b    = blockIdx.x >> 4;
    const int tile = blockIdx.x & 15;
    const float* xb = x + (size_t)b * C_ * N_ + (size_t)tile * 1024;

    const int jL  = t & 31;          // loader: column
    const int cL  = t >> 5;          // loader: channel part (0..15)
    const int kG  = t & 63;          // logits/softmax: cluster = lane
    const int wav = t >> 6;          // wave id = column-group
    const int j0  = wav * 4;
    const int tc  = t & 31;          // phase-B: channel lane
    const int tk  = t >> 5;          // phase-B: k-quad (0..15)

    const float lbias = ab[kG];

    float acc[4][8];                 // [k-sub][c-sub] aggregation accumulators
    #pragma unroll
    for (int i = 0; i < 4; ++i)
        #pragma unroll
        for (int u = 0; u < 8; ++u) acc[i][u] = 0.f;
    float asum_reg = 0.f;            // per-wave partial of asum[k = lane]

    for (int chunk = 0; chunk < 32; ++chunk) {
        const int n0 = chunk * 32;
        float lgacc[4] = {0.f, 0.f, 0.f, 0.f};
        float sq = 0.f;

        // ---- Phase A: stream 8 c-blocks: norms + logits partials ----
        for (int cb = 0; cb < 8; ++cb) {
            __syncthreads();
            float v0 = xb[(size_t)(cb * 32 + cL) * N_ + n0 + jL];
            float v1 = xb[(size_t)(cb * 32 + cL + 16) * N_ + n0 + jL];
            xA[jL][cL]      = v0;
            xA[jL][cL + 16] = v1;
            sq += v0 * v0 + v1 * v1;
            {
                const int cw = t & 31;
                const int kr = t >> 5;   // 0..15
                #pragma unroll
                for (int m = 0; m < 4; ++m)
                    wA[kr + 16 * m][cw] = aw[(size_t)(kr + 16 * m) * C_ + cb * 32 + cw];
            }
            __syncthreads();
            #pragma unroll
            for (int c4 = 0; c4 < 8; ++c4) {
                float4 w4 = *(const float4*)&wA[kG][c4 * 4];
                #pragma unroll
                for (int u = 0; u < 4; ++u) {
                    float4 x4 = *(const float4*)&xA[j0 + u][c4 * 4];  // broadcast
                    lgacc[u] += w4.x * x4.x + w4.y * x4.y + w4.z * x4.z + w4.w * x4.w;
                }
            }
        }

        // ---- column norms ----
        __syncthreads();
        colsq[cL][jL] = sq;
        __syncthreads();
        if (t < 32) {
            float s = 0.f;
            #pragma unroll
            for (int p = 0; p < 16; ++p) s += colsq[p][t];
            rnorm_s[t] = 1.0f / fmaxf(sqrtf(s), 1e-12f);
        }
        __syncthreads();

        // ---- softmax over k (= full wave), 4 columns per wave ----
        {
            float rn[4], lv[4];
            #pragma unroll
            for (int u = 0; u < 4; ++u) {
                rn[u] = rnorm_s[j0 + u];
                lv[u] = lgacc[u] * rn[u] + lbias;
            }
            float mx[4] = {lv[0], lv[1], lv[2], lv[3]};
            #pragma unroll
            for (int off = 32; off >= 1; off >>= 1)
                #pragma unroll
                for (int u = 0; u < 4; ++u)
                    mx[u] = fmaxf(mx[u], __shfl_xor(mx[u], off));
            float e[4], sm[4];
            #pragma unroll
            for (int u = 0; u < 4; ++u) { e[u] = __expf(lv[u] - mx[u]); sm[u] = e[u]; }
            #pragma unroll
            for (int off = 32; off >= 1; off >>= 1)
                #pragma unroll
                for (int u = 0; u < 4; ++u)
                    sm[u] += __shfl_xor(sm[u], off);
            #pragma unroll
            for (int u = 0; u < 4; ++u) {
                float a = e[u] / sm[u];
                asum_reg += a;
                lgs[kG][j0 + u] = a * rn[u];     // fold rnorm into a'
            }
        }
        __syncthreads();

        // ---- Phase B: aggregation, re-read x (L2-hot), 2 c-blocks of 128 ----
        #pragma unroll
        for (int cb2 = 0; cb2 < 2; ++cb2) {
            __syncthreads();
            #pragma unroll
            for (int i = 0; i < 8; ++i) {
                int cp = cL + 16 * i;
                xB[cp][jL] = xb[(size_t)(cb2 * 128 + cp) * N_ + n0 + jL];
            }
            __syncthreads();
            #pragma unroll 4
            for (int j = 0; j < 32; ++j) {
                float a0 = lgs[tk * 4 + 0][j];
                float a1 = lgs[tk * 4 + 1][j];
                float a2 = lgs[tk * 4 + 2][j];
                float a3 = lgs[tk * 4 + 3][j];
                #pragma unroll
                for (int u = 0; u < 4; ++u) {
                    float xv = xB[tc + 32 * u][j];   // stride-33: conflict-free
                    acc[0][cb2 * 4 + u] += a0 * xv;
                    acc[1][cb2 * 4 + u] += a1 * xv;
                    acc[2][cb2 * 4 + u] += a2 * xv;
                    acc[3][cb2 * 4 + u] += a3 * xv;
                }
            }
        }
    }

    // ---- epilogue: reduce asum across waves, atomic out ----
    __syncthreads();
    awred[wav][kG] = asum_reg;
    __syncthreads();
    if (t < 64) {
        float s = 0.f;
        #pragma unroll
        for (int w = 0; w < 8; ++w) s += awred[w][t];
        atomicAdd(&asum[b * 64 + t], s);
    }
    #pragma unroll
    for (int i = 0; i < 4; ++i)
        #pragma unroll
        for (int cb2 = 0; cb2 < 2; ++cb2)
            #pragma unroll
            for (int u = 0; u < 4; ++u) {
                int k = tk * 4 + i;
                int c = cb2 * 128 + tc + 32 * u;
                atomicAdd(&agg[((size_t)(b * 64 + k)) * 256 + c], acc[i][cb2 * 4 + u]);
            }
}

// ---------------------------------------------------------------------------
// K2a: vlad = agg - asum*centroid, intra-norm over C, accumulate global norm.
// Grid: B*K blocks x 64 threads (one wave per (b,k) row).
// ---------------------------------------------------------------------------
__global__ void k2a_vlad_norm(const float* __restrict__ agg,
                              const float* __restrict__ asum,
                              const float* __restrict__ cent,
                              float* __restrict__ vn,
                              float* __restrict__ gsq)
{
    const int b = blockIdx.x >> 6;
    const int k = blockIdx.x & 63;
    const int lane = threadIdx.x;
    const float as = asum[b * 64 + k];
    float v[4];
    float sq = 0.f;
    #pragma unroll
    for (int i = 0; i < 4; ++i) {
        int c = lane + 64 * i;
        v[i] = agg[((size_t)(b * 64 + k)) * 256 + c] - as * cent[k * 256 + c];
        sq += v[i] * v[i];
    }
    #pragma unroll
    for (int off = 32; off >= 1; off >>= 1) sq += __shfl_xor(sq, off);
    float scale = 1.0f / fmaxf(sqrtf(sq), 1e-12f);
    #pragma unroll
    for (int i = 0; i < 4; ++i) {
        int c = lane + 64 * i;
        vn[(size_t)b * 16384 + k * 256 + c] = v[i] * scale;
    }
    if (lane == 0) atomicAdd(&gsq[b], sq * scale * scale);
}

// ---------------------------------------------------------------------------
// K2b: y[b,co] = (vn[b,:]/gnorm[b]) . red_w[co,:] + red_b[co]
// Grid: 128 blocks x 256 thr; each block: 4 co, all 16 b (vn stays L2-hot).
// ---------------------------------------------------------------------------
__global__ __launch_bounds__(256) void k2b_gemm(
    const float* __restrict__ vn, const float* __restrict__ gsq,
    const float* __restrict__ rw, const float* __restrict__ rb,
    float* __restrict__ y)
{
    __shared__ float part[4][4][16];   // [wave][u][b]
    const int t = threadIdx.x;
    const int co0 = blockIdx.x * 4;
    float accv[4][16];
    #pragma unroll
    for (int u = 0; u < 4; ++u)
        #pragma unroll
        for (int bb = 0; bb < 16; ++bb) accv[u][bb] = 0.f;

    for (int m = 0; m < 64; ++m) {
        int i = m * 256 + t;
        float w0 = rw[(size_t)(co0 + 0) * 16384 + i];
        float w1 = rw[(size_t)(co0 + 1) * 16384 + i];
        float w2 = rw[(size_t)(co0 + 2) * 16384 + i];
        float w3 = rw[(size_t)(co0 + 3) * 16384 + i];
        #pragma unroll
        for (int bb = 0; bb < 16; ++bb) {
            float v = vn[(size_t)bb * 16384 + i];
            accv[0][bb] += w0 * v;
            accv[1][bb] += w1 * v;
            accv[2][bb] += w2 * v;
            accv[3][bb] += w3 * v;
        }
    }
    // full-wave butterfly: every lane ends with all 64 (u,b) wave-sums
    #pragma unroll
    for (int off = 32; off >= 1; off >>= 1)
        #pragma unroll
        for (int u = 0; u < 4; ++u)
            #pragma unroll
            for (int bb = 0; bb < 16; ++bb)
                accv[u][bb] += __shfl_xor(accv[u][bb], off);
    const int wav = t >> 6, lane = t & 63;
    part[wav][lane >> 4][lane & 15] = accv[lane >> 4][lane & 15];
    __syncthreads();
    if (t < 64) {
        int u = t >> 4, bb = t & 15;
        float s = part[0][u][bb] + part[1][u][bb] + part[2][u][bb] + part[3][u][bb];
        float g = fmaxf(sqrtf(gsq[bb]), 1e-12f);
        y[bb * 512 + co0 + u] = s / g + rb[co0 + u];
    }
}

// ---------------------------------------------------------------------------
// K2c: BatchNorm1d (training stats over B) + ReLU. One block, 512 threads.
// ---------------------------------------------------------------------------
__global__ void k2c_bn(const float* __restrict__ y,
                       const float* __restrict__ bnw,
                       const float* __restrict__ bnb,
                       float* __restrict__ out)
{
    const int co = threadIdx.x;
    float vals[16];
    float m = 0.f;
    #pragma unroll
    for (int bb = 0; bb < 16; ++bb) {
        vals[bb] = y[bb * 512 + co];
        m += vals[bb];
    }
    m *= (1.0f / 16.0f);
    float var = 0.f;
    #pragma unroll
    for (int bb = 0; bb < 16; ++bb) {
        float d = vals[bb] - m;
        var += d * d;
    }
    var *= (1.0f / 16.0f);
    float inv = 1.0f / sqrtf(var + 1e-5f);
    float w = bnw[co], bias = bnb[co];
    #pragma unroll
    for (int bb = 0; bb < 16; ++bb) {
        float o = w * (vals[bb] - m) * inv + bias;
        out[bb * 512 + co] = fmaxf(o, 0.f);
    }
}

// ---------------------------------------------------------------------------
extern "C" void kernel_launch(void* const* d_in, const int* in_sizes, int n_in,
                              void* d_out, int out_size, void* d_ws, size_t ws_size,
                              hipStream_t stream)
{
    const float* x    = (const float*)d_in[0];
    const float* aw   = (const float*)d_in[1];
    const float* ab   = (const float*)d_in[2];
    const float* cent = (const float*)d_in[3];
    const float* rw   = (const float*)d_in[4];
    const float* rb   = (const float*)d_in[5];
    const float* bnw  = (const float*)d_in[6];
    const float* bnb  = (const float*)d_in[7];
    float* out = (float*)d_out;

    char* ws = (char*)d_ws;
    float* agg  = (float*)(ws);                         // 1,048,576 B
    float* asum = (float*)(ws + 1048576);               // 4,096 B
    float* gsq  = (float*)(ws + 1052672);               // 64 B (+pad)
    float* vn   = (float*)(ws + 1056768);               // 1,048,576 B
    float* y    = (float*)(ws + 1056768 + 1048576);     // 32,768 B

    // zero the atomic accumulators (agg + asum + gsq)
    hipMemsetAsync(ws, 0, 1056768, stream);

    hipLaunchKernelGGL(k1_assign_agg, dim3(256), dim3(512), 0, stream,
                       x, aw, ab, agg, asum);
    hipLaunchKernelGGL(k2a_vlad_norm, dim3(B_ * K_), dim3(64), 0, stream,
                       agg, asum, cent, vn, gsq);
    hipLaunchKernelGGL(k2b_gemm, dim3(128), dim3(256), 0, stream,
                       vn, gsq, rw, rb, y);
    hipLaunchKernelGGL(k2c_bn, dim3(1), dim3(512), 0, stream,
                       y, bnw, bnb, out);
}

// Round 2
// 540.387 us; speedup vs baseline: 2.3163x; 2.3163x over previous
//
#include <hip/hip_runtime.h>
#include <math.h>

#define B_   16
#define C_   256
#define N_   16384
#define K_   64
#define CO_  512

typedef __attribute__((ext_vector_type(8))) short short8;
typedef __attribute__((ext_vector_type(4))) float floatx4;

__device__ inline unsigned short f2bf(float f) {
    unsigned int u = __float_as_uint(f);
    u = (u + 0x7FFFu + ((u >> 16) & 1u)) >> 16;   // RNE (inputs finite)
    return (unsigned short)u;
}
__device__ inline float bf2f(unsigned short h) {
    return __uint_as_float(((unsigned int)h) << 16);
}

// ---------------------------------------------------------------------------
// K1: fused l2norm -> logits(MFMA) -> softmax -> aggregation(MFMA)
// 512 blocks (2/CU), 512 threads. Each block: 512 n-columns, 8 chunks of 64.
// LDS: x_cn[256][72]bf16 (36864) + x_nc[64][264]bf16 (33792) +
//      a_ld[64][72]bf16 (9216) + misc 1280 = 81152 B  -> 2 blocks/CU.
// ---------------------------------------------------------------------------
__global__ __launch_bounds__(512, 4) void k1_assign_agg(
    const float* __restrict__ x, const float* __restrict__ aw,
    const float* __restrict__ ab, float* __restrict__ agg,
    float* __restrict__ asum)
{
    __shared__ __align__(16) unsigned char smem[81152];
    unsigned short* x_cn  = (unsigned short*)smem;             // [256][72]
    unsigned short* x_nc  = (unsigned short*)(smem + 36864);   // [64][264]
    unsigned short* a_ld  = (unsigned short*)(smem + 70656);   // [64][72]
    unsigned short* colsq = (unsigned short*)(smem + 79872);   // [64][8] bf16
    float* rnorm = (float*)(smem + 79872);                     // [64] f32 (overlay after colsq read)
    float* part  = (float*)(smem + 79872 + 256);               // [64][4] f32
    float* red   = part;                                       // [8][16] f32 (epilogue)

    const int t    = threadIdx.x;
    const int lane = t & 63;
    const int wav  = t >> 6;           // 0..7
    const int b    = blockIdx.x >> 5;
    const int tile = blockIdx.x & 31;
    const float* xb = x + (size_t)b * ((size_t)C_ * N_) + tile * 512;

    const int j16 = lane & 15;
    const int g4  = lane >> 4;         // 0..3
    const int mw  = wav & 3;           // phase A: k-tile
    const int jw  = wav >> 2;          // phase A: j-half

    // hoisted w A-fragments (m-tile mw) + bias
    short8 wf[8];
    {
        const float* wrow = aw + (mw * 16 + j16) * 256 + g4 * 8;
        #pragma unroll
        for (int ki = 0; ki < 8; ++ki) {
            const float* p = wrow + ki * 32;
            short8 f;
            #pragma unroll
            for (int i = 0; i < 8; ++i) f[i] = (short)f2bf(p[i]);
            wf[ki] = f;
        }
    }
    const float4 abf = *(const float4*)(ab + mw * 16 + g4 * 4);

    floatx4 acc[4][2];
    #pragma unroll
    for (int m = 0; m < 4; ++m)
        #pragma unroll
        for (int c2 = 0; c2 < 2; ++c2)
            acc[m][c2] = (floatx4){0.f, 0.f, 0.f, 0.f};
    float asr[4] = {0.f, 0.f, 0.f, 0.f};

    const int nL = t & 63;             // staging: column
    const int cg = t >> 6;             // staging: c-group

    for (int chunk = 0; chunk < 8; ++chunk) {
        const int n0 = chunk * 64;
        __syncthreads();                               // B0: prev chunk consumed
        // ---- stage x chunk: both LDS layouts + column sumsq ----
        {
            const float* src = xb + n0 + nL;
            unsigned int* nc_row = (unsigned int*)(x_nc + nL * 264);
            float sq = 0.f;
            #pragma unroll
            for (int i = 0; i < 16; ++i) {
                int c0 = cg * 32 + 2 * i;
                float f0 = src[(size_t)c0 * N_];
                float f1 = src[(size_t)(c0 + 1) * N_];
                sq += f0 * f0 + f1 * f1;
                unsigned int h0 = f2bf(f0), h1 = f2bf(f1);
                x_cn[c0 * 72 + nL]       = (unsigned short)h0;
                x_cn[(c0 + 1) * 72 + nL] = (unsigned short)h1;
                nc_row[cg * 16 + i] = h0 | (h1 << 16);
            }
            colsq[nL * 8 + cg] = f2bf(sq);
        }
        __syncthreads();                               // B1
        if (t < 64) {
            short8 cs = *(const short8*)(colsq + t * 8);
            float s = 0.f;
            #pragma unroll
            for (int i = 0; i < 8; ++i) s += bf2f((unsigned short)cs[i]);
            rnorm[t] = 1.0f / fmaxf(sqrtf(s), 1e-12f); // overlay-safe: wave-lockstep
        }
        __syncthreads();                               // B2
        // ---- phase A: logits = w . x  (MFMA, reduce over c) ----
        floatx4 ct0 = {0.f, 0.f, 0.f, 0.f}, ct1 = {0.f, 0.f, 0.f, 0.f};
        {
            const unsigned short* r0 = x_nc + (jw * 32 + j16) * 264 + g4 * 8;
            const unsigned short* r1 = r0 + 16 * 264;
            #pragma unroll
            for (int ki = 0; ki < 8; ++ki) {
                short8 b0 = *(const short8*)(r0 + ki * 32);
                short8 b1 = *(const short8*)(r1 + ki * 32);
                ct0 = __builtin_amdgcn_mfma_f32_16x16x32_bf16(wf[ki], b0, ct0, 0, 0, 0);
                ct1 = __builtin_amdgcn_mfma_f32_16x16x32_bf16(wf[ki], b1, ct1, 0, 0, 0);
            }
        }
        // ---- softmax over k=64 (logits are O(1): no max subtraction) ----
        const float rn0 = rnorm[jw * 32 + j16];
        const float rn1 = rnorm[jw * 32 + 16 + j16];
        float e0[4], e1[4];
        float p0 = 0.f, p1 = 0.f;
        #pragma unroll
        for (int r = 0; r < 4; ++r) {
            float l0 = ct0[r] * rn0 + ((const float*)&abf)[r];
            float l1 = ct1[r] * rn1 + ((const float*)&abf)[r];
            e0[r] = __expf(l0); e1[r] = __expf(l1);
            p0 += e0[r]; p1 += e1[r];
        }
        p0 += __shfl_xor(p0, 16); p0 += __shfl_xor(p0, 32);
        p1 += __shfl_xor(p1, 16); p1 += __shfl_xor(p1, 32);
        if (lane < 16) {
            part[(jw * 32 + j16) * 4 + mw]      = p0;
            part[(jw * 32 + 16 + j16) * 4 + mw] = p1;
        }
        __syncthreads();                               // B3
        {
            float4 q0 = *(const float4*)(part + (jw * 32 + j16) * 4);
            float4 q1 = *(const float4*)(part + (jw * 32 + 16 + j16) * 4);
            float i0 = 1.0f / (q0.x + q0.y + q0.z + q0.w);
            float i1 = 1.0f / (q1.x + q1.y + q1.z + q1.w);
            float s0 = rn0 * i0, s1 = rn1 * i1;
            unsigned short* arow = a_ld + (mw * 16 + g4 * 4) * 72;
            #pragma unroll
            for (int r = 0; r < 4; ++r) {
                arow[r * 72 + jw * 32 + j16]      = f2bf(e0[r] * s0);
                arow[r * 72 + jw * 32 + 16 + j16] = f2bf(e1[r] * s1);
                asr[r] += e0[r] * i0 + e1[r] * i1;
            }
        }
        __syncthreads();                               // B4
        // ---- phase B: agg += a' . x^T  (MFMA, reduce over n) ----
        {
            const int cb = wav * 32;
            #pragma unroll
            for (int ki = 0; ki < 2; ++ki) {
                const int nn = ki * 32 + g4 * 8;
                short8 af[4];
                #pragma unroll
                for (int m = 0; m < 4; ++m)
                    af[m] = *(const short8*)(a_ld + (m * 16 + j16) * 72 + nn);
                #pragma unroll
                for (int c2 = 0; c2 < 2; ++c2) {
                    short8 bfv = *(const short8*)(x_cn + (cb + c2 * 16 + j16) * 72 + nn);
                    #pragma unroll
                    for (int m = 0; m < 4; ++m)
                        acc[m][c2] = __builtin_amdgcn_mfma_f32_16x16x32_bf16(af[m], bfv, acc[m][c2], 0, 0, 0);
                }
            }
        }
    }

    // ---- epilogue: asum reduce + one atomic flush of agg ----
    __syncthreads();
    #pragma unroll
    for (int r = 0; r < 4; ++r) {
        asr[r] += __shfl_xor(asr[r], 1);
        asr[r] += __shfl_xor(asr[r], 2);
        asr[r] += __shfl_xor(asr[r], 4);
        asr[r] += __shfl_xor(asr[r], 8);
    }
    if (j16 == 0) {
        #pragma unroll
        for (int r = 0; r < 4; ++r) red[wav * 16 + g4 * 4 + r] = asr[r];
    }
    __syncthreads();
    if (t < 64) {
        float s = red[(t >> 4) * 16 + (t & 15)] + red[((t >> 4) + 4) * 16 + (t & 15)];
        atomicAdd(&asum[b * 64 + t], s);
    }
    #pragma unroll
    for (int m = 0; m < 4; ++m)
        #pragma unroll
        for (int c2 = 0; c2 < 2; ++c2)
            #pragma unroll
            for (int r = 0; r < 4; ++r) {
                int k = m * 16 + g4 * 4 + r;
                int c = wav * 32 + c2 * 16 + j16;
                atomicAdd(&agg[((size_t)(b * 64 + k)) * 256 + c], acc[m][c2][r]);
            }
}

// ---------------------------------------------------------------------------
// K2a: vlad = agg - asum*cent, intra-norm over C, accumulate global norm.
// ---------------------------------------------------------------------------
__global__ void k2a_vlad_norm(const float* __restrict__ agg,
                              const float* __restrict__ asum,
                              const float* __restrict__ cent,
                              float* __restrict__ vn,
                              float* __restrict__ gsq)
{
    const int b = blockIdx.x >> 6;
    const int k = blockIdx.x & 63;
    const int lane = threadIdx.x;
    const float as = asum[b * 64 + k];
    float v[4];
    float sq = 0.f;
    #pragma unroll
    for (int i = 0; i < 4; ++i) {
        int c = lane + 64 * i;
        v[i] = agg[((size_t)(b * 64 + k)) * 256 + c] - as * cent[k * 256 + c];
        sq += v[i] * v[i];
    }
    #pragma unroll
    for (int off = 32; off >= 1; off >>= 1) sq += __shfl_xor(sq, off);
    float scale = 1.0f / fmaxf(sqrtf(sq), 1e-12f);
    #pragma unroll
    for (int i = 0; i < 4; ++i) {
        int c = lane + 64 * i;
        vn[(size_t)b * 16384 + k * 256 + c] = v[i] * scale;
    }
    if (lane == 0) atomicAdd(&gsq[b], sq * scale * scale);
}

// ---------------------------------------------------------------------------
// K2b: y[b,co] = (vn[b,:]/gnorm[b]) . red_w[co,:] + red_b[co]   (fp32!)
// 256 blocks x 256 thr, 2 co per block, float4 loads.
// ---------------------------------------------------------------------------
__global__ __launch_bounds__(256) void k2b_gemm(
    const float* __restrict__ vn, const float* __restrict__ gsq,
    const float* __restrict__ rw, const float* __restrict__ rb,
    float* __restrict__ y)
{
    __shared__ float pr[4][2][16];
    const int t = threadIdx.x;
    const int co0 = blockIdx.x * 2;
    const float4* rw4 = (const float4*)rw;
    const float4* vn4 = (const float4*)vn;
    float a0[16], a1[16];
    #pragma unroll
    for (int bb = 0; bb < 16; ++bb) { a0[bb] = 0.f; a1[bb] = 0.f; }
    for (int it = 0; it < 16; ++it) {
        int idx = it * 256 + t;
        float4 wa = rw4[(size_t)co0 * 4096 + idx];
        float4 wb = rw4[(size_t)(co0 + 1) * 4096 + idx];
        #pragma unroll
        for (int bb = 0; bb < 16; ++bb) {
            float4 v = vn4[(size_t)bb * 4096 + idx];
            a0[bb] += wa.x * v.x + wa.y * v.y + wa.z * v.z + wa.w * v.w;
            a1[bb] += wb.x * v.x + wb.y * v.y + wb.z * v.z + wb.w * v.w;
        }
    }
    #pragma unroll
    for (int off = 32; off >= 1; off >>= 1)
        #pragma unroll
        for (int bb = 0; bb < 16; ++bb) {
            a0[bb] += __shfl_xor(a0[bb], off);
            a1[bb] += __shfl_xor(a1[bb], off);
        }
    const int wav = t >> 6, lane = t & 63;
    if (lane < 16) { pr[wav][0][lane] = a0[lane]; pr[wav][1][lane] = a1[lane]; }
    __syncthreads();
    if (t < 32) {
        int u = t >> 4, bb = t & 15;
        float s = pr[0][u][bb] + pr[1][u][bb] + pr[2][u][bb] + pr[3][u][bb];
        float g = fmaxf(sqrtf(gsq[bb]), 1e-12f);
        y[bb * 512 + co0 + u] = s / g + rb[co0 + u];
    }
}

// ---------------------------------------------------------------------------
// K2c: BatchNorm1d (batch stats) + ReLU. One block, 512 threads.
// ---------------------------------------------------------------------------
__global__ void k2c_bn(const float* __restrict__ y,
                       const float* __restrict__ bnw,
                       const float* __restrict__ bnb,
                       float* __restrict__ out)
{
    const int co = threadIdx.x;
    float vals[16];
    float m = 0.f;
    #pragma unroll
    for (int bb = 0; bb < 16; ++bb) {
        vals[bb] = y[bb * 512 + co];
        m += vals[bb];
    }
    m *= (1.0f / 16.0f);
    float var = 0.f;
    #pragma unroll
    for (int bb = 0; bb < 16; ++bb) {
        float d = vals[bb] - m;
        var += d * d;
    }
    var *= (1.0f / 16.0f);
    float inv = 1.0f / sqrtf(var + 1e-5f);
    float w = bnw[co], bias = bnb[co];
    #pragma unroll
    for (int bb = 0; bb < 16; ++bb) {
        float o = w * (vals[bb] - m) * inv + bias;
        out[bb * 512 + co] = fmaxf(o, 0.f);
    }
}

// ---------------------------------------------------------------------------
extern "C" void kernel_launch(void* const* d_in, const int* in_sizes, int n_in,
                              void* d_out, int out_size, void* d_ws, size_t ws_size,
                              hipStream_t stream)
{
    const float* x    = (const float*)d_in[0];
    const float* aw   = (const float*)d_in[1];
    const float* ab   = (const float*)d_in[2];
    const float* cent = (const float*)d_in[3];
    const float* rw   = (const float*)d_in[4];
    const float* rb   = (const float*)d_in[5];
    const float* bnw  = (const float*)d_in[6];
    const float* bnb  = (const float*)d_in[7];
    float* out = (float*)d_out;

    char* ws = (char*)d_ws;
    float* agg  = (float*)(ws);                         // 1,048,576 B
    float* asum = (float*)(ws + 1048576);               // 4,096 B
    float* gsq  = (float*)(ws + 1052672);               // 64 B (+pad)
    float* vn   = (float*)(ws + 1056768);               // 1,048,576 B
    float* y    = (float*)(ws + 1056768 + 1048576);     // 32,768 B

    hipMemsetAsync(ws, 0, 1056768, stream);             // zero agg+asum+gsq

    hipLaunchKernelGGL(k1_assign_agg, dim3(512), dim3(512), 0, stream,
                       x, aw, ab, agg, asum);
    hipLaunchKernelGGL(k2a_vlad_norm, dim3(B_ * K_), dim3(64), 0, stream,
                       agg, asum, cent, vn, gsq);
    hipLaunchKernelGGL(k2b_gemm, dim3(256), dim3(256), 0, stream,
                       vn, gsq, rw, rb, y);
    hipLaunchKernelGGL(k2c_bn, dim3(1), dim3(512), 0, stream,
                       y, bnw, bnb, out);
}

// Round 3
// 523.528 us; speedup vs baseline: 2.3909x; 1.0322x over previous
//
#include <hip/hip_runtime.h>
#include <math.h>

#define B_   16
#define C_   256
#define N_   16384
#define K_   64
#define CO_  512

typedef __attribute__((ext_vector_type(8))) short short8;
typedef __attribute__((ext_vector_type(4))) short short4v;
typedef __attribute__((ext_vector_type(4))) float floatx4;

__device__ inline unsigned int f2bf(float f) {
    unsigned int u = __float_as_uint(f);
    return (u + 0x7FFFu + ((u >> 16) & 1u)) >> 16;   // RNE (inputs finite)
}

// XOR-swizzled [row][64col] bf16 LDS tile: conflict-free writes (n-pairs across
// lanes) and conflict-free b128 reads (8 consecutive cols per lane).
// phys_sh(row,col) = row*64 + (((col>>2) ^ (row&14))<<2) + (col&3)

// ---------------------------------------------------------------------------
// K1: fused l2norm -> logits(MFMA) -> softmax -> aggregation(MFMA)
// 512 blocks (2/CU), 512 threads, 8 chunks of 64 columns, register-prefetch
// software pipeline (chunk k+1 global loads in flight across chunk k's barriers).
// LDS 79,872 B -> 2 blocks/CU.
// ---------------------------------------------------------------------------
__global__ __launch_bounds__(512, 4) void k1_assign_agg(
    const float* __restrict__ x, const float* __restrict__ aw,
    const float* __restrict__ ab, float* __restrict__ agg,
    float* __restrict__ asum)
{
    __shared__ __align__(16) unsigned char smem[79872];
    unsigned short* x_cn = (unsigned short*)smem;              // [256][64] swizzled, 32768
    unsigned short* x_nc = (unsigned short*)(smem + 32768);    // [64][260], 33280
    unsigned short* a_ld = (unsigned short*)(smem + 66048);    // [64][64] swizzled, 8192
    float* colsq = (float*)(smem + 74240);                     // [64][17], 4352
    float* rnorm = (float*)(smem + 78592);                     // [64], 256
    float* part  = (float*)(smem + 78848);                     // [64][4], 1024
    float* red   = part;                                       // [8][16] epilogue overlay

    const int t    = threadIdx.x;
    const int lane = t & 63;
    const int wav  = t >> 6;
    const int b    = blockIdx.x >> 5;
    const int tile = blockIdx.x & 31;
    const float* xb = x + (size_t)b * ((size_t)C_ * N_) + tile * 512;

    const int j16 = lane & 15;
    const int g4  = lane >> 4;         // 0..3
    const int mw  = wav & 3;           // phase A: k-tile
    const int jw  = wav >> 2;          // phase A: j-half
    const int p   = t & 31;            // staging: n-pair
    const int g   = t >> 5;            // staging: c-group (0..15)

    // hoisted w A-fragments + bias
    short8 wf[8];
    {
        const float* wrow = aw + (mw * 16 + j16) * 256 + g4 * 8;
        #pragma unroll
        for (int ki = 0; ki < 8; ++ki) {
            const float* q = wrow + ki * 32;
            short8 f;
            #pragma unroll
            for (int i = 0; i < 8; ++i) f[i] = (short)f2bf(q[i]);
            wf[ki] = f;
        }
    }
    const float4 abf = *(const float4*)(ab + mw * 16 + g4 * 4);

    floatx4 acc[4][2];
    #pragma unroll
    for (int m = 0; m < 4; ++m)
        #pragma unroll
        for (int c2 = 0; c2 < 2; ++c2)
            acc[m][c2] = (floatx4){0.f, 0.f, 0.f, 0.f};
    float asr[4] = {0.f, 0.f, 0.f, 0.f};

    // ---- prologue: prefetch chunk 0 into registers ----
    float2 v[16];
    {
        const float* ps = xb + 2 * p;
        #pragma unroll
        for (int i = 0; i < 16; ++i)
            v[i] = *(const float2*)(ps + (size_t)(g * 16 + i) * N_);
    }

    for (int chunk = 0; chunk < 8; ++chunk) {
        __syncthreads();                               // B0: prev chunk's LDS consumed
        // ---- stage prefetched regs -> LDS (both layouts) + col sumsq ----
        float sq0 = 0.f, sq1 = 0.f;
        #pragma unroll
        for (int half = 0; half < 2; ++half) {
            unsigned int hL[8], hH[8];
            #pragma unroll
            for (int i = 0; i < 8; ++i) {
                float2 vv = v[half * 8 + i];
                sq0 += vv.x * vv.x; sq1 += vv.y * vv.y;
                hL[i] = f2bf(vv.x); hH[i] = f2bf(vv.y);
                int c = g * 16 + half * 8 + i;
                ((unsigned int*)x_cn)[c * 32 + (((p >> 1) ^ (c & 14)) << 1) + (p & 1)]
                    = hL[i] | (hH[i] << 16);
            }
            unsigned short* r0 = x_nc + (2 * p) * 260 + g * 16 + half * 8;
            unsigned short* r1 = r0 + 260;
            uint2 wl0, wl1, wh0, wh1;
            wl0.x = hL[0] | (hL[1] << 16); wl0.y = hL[2] | (hL[3] << 16);
            wl1.x = hL[4] | (hL[5] << 16); wl1.y = hL[6] | (hL[7] << 16);
            wh0.x = hH[0] | (hH[1] << 16); wh0.y = hH[2] | (hH[3] << 16);
            wh1.x = hH[4] | (hH[5] << 16); wh1.y = hH[6] | (hH[7] << 16);
            *(uint2*)(r0 + 0) = wl0; *(uint2*)(r0 + 4) = wl1;
            *(uint2*)(r1 + 0) = wh0; *(uint2*)(r1 + 4) = wh1;
        }
        colsq[(2 * p) * 17 + g]     = sq0;
        colsq[(2 * p + 1) * 17 + g] = sq1;
        // ---- issue next chunk's global loads (in flight across barriers) ----
        if (chunk < 7) {
            const float* ps = xb + (chunk + 1) * 64 + 2 * p;
            #pragma unroll
            for (int i = 0; i < 16; ++i)
                v[i] = *(const float2*)(ps + (size_t)(g * 16 + i) * N_);
        }
        __syncthreads();                               // B1
        if (t < 64) {
            float s = 0.f;
            #pragma unroll
            for (int q = 0; q < 16; ++q) s += colsq[t * 17 + q];
            rnorm[t] = 1.0f / fmaxf(sqrtf(s), 1e-12f);
        }
        __syncthreads();                               // B2
        // ---- phase A: logits = w . xn (MFMA over c) ----
        floatx4 ct0 = {0.f, 0.f, 0.f, 0.f}, ct1 = {0.f, 0.f, 0.f, 0.f};
        {
            const unsigned short* rA0 = x_nc + (jw * 32 + j16) * 260 + g4 * 8;
            const unsigned short* rA1 = rA0 + 16 * 260;
            #pragma unroll
            for (int ki = 0; ki < 8; ++ki) {
                short4v a0 = *(const short4v*)(rA0 + ki * 32);
                short4v a1 = *(const short4v*)(rA0 + ki * 32 + 4);
                short4v b0 = *(const short4v*)(rA1 + ki * 32);
                short4v b1 = *(const short4v*)(rA1 + ki * 32 + 4);
                short8 f0, f1;
                #pragma unroll
                for (int i = 0; i < 4; ++i) {
                    f0[i] = a0[i]; f0[i + 4] = a1[i];
                    f1[i] = b0[i]; f1[i + 4] = b1[i];
                }
                ct0 = __builtin_amdgcn_mfma_f32_16x16x32_bf16(wf[ki], f0, ct0, 0, 0, 0);
                ct1 = __builtin_amdgcn_mfma_f32_16x16x32_bf16(wf[ki], f1, ct1, 0, 0, 0);
            }
        }
        // ---- softmax over k=64 ----
        const float rn0 = rnorm[jw * 32 + j16];
        const float rn1 = rnorm[jw * 32 + 16 + j16];
        float e0[4], e1[4];
        float p0 = 0.f, p1 = 0.f;
        #pragma unroll
        for (int r = 0; r < 4; ++r) {
            float l0 = ct0[r] * rn0 + ((const float*)&abf)[r];
            float l1 = ct1[r] * rn1 + ((const float*)&abf)[r];
            e0[r] = __expf(l0); e1[r] = __expf(l1);
            p0 += e0[r]; p1 += e1[r];
        }
        p0 += __shfl_xor(p0, 16); p0 += __shfl_xor(p0, 32);
        p1 += __shfl_xor(p1, 16); p1 += __shfl_xor(p1, 32);
        if (lane < 16) {
            part[(jw * 32 + j16) * 4 + mw]      = p0;
            part[(jw * 32 + 16 + j16) * 4 + mw] = p1;
        }
        __syncthreads();                               // B3
        {
            float4 q0 = *(const float4*)(part + (jw * 32 + j16) * 4);
            float4 q1 = *(const float4*)(part + (jw * 32 + 16 + j16) * 4);
            float i0 = 1.0f / (q0.x + q0.y + q0.z + q0.w);
            float i1 = 1.0f / (q1.x + q1.y + q1.z + q1.w);
            float s0 = rn0 * i0, s1 = rn1 * i1;
            const int n0c = jw * 32 + j16, n1c = n0c + 16;
            #pragma unroll
            for (int r = 0; r < 4; ++r) {
                int k = mw * 16 + g4 * 4 + r;
                a_ld[k * 64 + ((((n0c) >> 2) ^ (k & 14)) << 2) + (n0c & 3)]
                    = (unsigned short)f2bf(e0[r] * s0);
                a_ld[k * 64 + ((((n1c) >> 2) ^ (k & 14)) << 2) + (n1c & 3)]
                    = (unsigned short)f2bf(e1[r] * s1);
                asr[r] += e0[r] * i0 + e1[r] * i1;
            }
        }
        __syncthreads();                               // B4
        // ---- phase B: agg += a' . xn^T (MFMA over n) ----
        {
            const int cb = wav * 32;
            #pragma unroll
            for (int ki = 0; ki < 2; ++ki) {
                const int sub = ki * 8 + g4 * 2;       // even
                short8 af[4];
                #pragma unroll
                for (int m = 0; m < 4; ++m) {
                    int k = m * 16 + j16;
                    af[m] = *(const short8*)&a_ld[k * 64 + ((sub ^ (k & 14)) << 2)];
                }
                #pragma unroll
                for (int c2 = 0; c2 < 2; ++c2) {
                    int c = cb + c2 * 16 + j16;
                    short8 bfv = *(const short8*)&x_cn[c * 64 + ((sub ^ (c & 14)) << 2)];
                    #pragma unroll
                    for (int m = 0; m < 4; ++m)
                        acc[m][c2] = __builtin_amdgcn_mfma_f32_16x16x32_bf16(af[m], bfv, acc[m][c2], 0, 0, 0);
                }
            }
        }
    }

    // ---- epilogue: asum reduce + one atomic flush of agg ----
    __syncthreads();
    #pragma unroll
    for (int r = 0; r < 4; ++r) {
        asr[r] += __shfl_xor(asr[r], 1);
        asr[r] += __shfl_xor(asr[r], 2);
        asr[r] += __shfl_xor(asr[r], 4);
        asr[r] += __shfl_xor(asr[r], 8);
    }
    if (j16 == 0) {
        #pragma unroll
        for (int r = 0; r < 4; ++r) red[wav * 16 + g4 * 4 + r] = asr[r];
    }
    __syncthreads();
    if (t < 64) {
        float s = red[(t >> 4) * 16 + (t & 15)] + red[((t >> 4) + 4) * 16 + (t & 15)];
        atomicAdd(&asum[b * 64 + t], s);
    }
    #pragma unroll
    for (int m = 0; m < 4; ++m)
        #pragma unroll
        for (int c2 = 0; c2 < 2; ++c2)
            #pragma unroll
            for (int r = 0; r < 4; ++r) {
                int k = m * 16 + g4 * 4 + r;
                int c = wav * 32 + c2 * 16 + j16;
                atomicAdd(&agg[((size_t)(b * 64 + k)) * 256 + c], acc[m][c2][r]);
            }
}

// ---------------------------------------------------------------------------
// K2a: vlad = agg - asum*cent, intra-norm over C, accumulate global norm.
// ---------------------------------------------------------------------------
__global__ void k2a_vlad_norm(const float* __restrict__ agg,
                              const float* __restrict__ asum,
                              const float* __restrict__ cent,
                              float* __restrict__ vn,
                              float* __restrict__ gsq)
{
    const int b = blockIdx.x >> 6;
    const int k = blockIdx.x & 63;
    const int lane = threadIdx.x;
    const float as = asum[b * 64 + k];
    float v[4];
    float sq = 0.f;
    #pragma unroll
    for (int i = 0; i < 4; ++i) {
        int c = lane + 64 * i;
        v[i] = agg[((size_t)(b * 64 + k)) * 256 + c] - as * cent[k * 256 + c];
        sq += v[i] * v[i];
    }
    #pragma unroll
    for (int off = 32; off >= 1; off >>= 1) sq += __shfl_xor(sq, off);
    float scale = 1.0f / fmaxf(sqrtf(sq), 1e-12f);
    #pragma unroll
    for (int i = 0; i < 4; ++i) {
        int c = lane + 64 * i;
        vn[(size_t)b * 16384 + k * 256 + c] = v[i] * scale;
    }
    if (lane == 0) atomicAdd(&gsq[b], sq * scale * scale);
}

// ---------------------------------------------------------------------------
// K2b: split-K partial dot: y[b,co] (+)= vn[b, half] . red_w[co, half]  (fp32)
// 1024 blocks (co x half) x 256 thr; global-norm + bias applied in k2c.
// ---------------------------------------------------------------------------
__global__ __launch_bounds__(256) void k2b_gemm(
    const float* __restrict__ vn, const float* __restrict__ rw,
    float* __restrict__ y)
{
    __shared__ float pr[4][16];
    const int t = threadIdx.x;
    const int co   = blockIdx.x >> 1;
    const int half = blockIdx.x & 1;
    const float4* rwr = (const float4*)rw + (size_t)co * 4096 + half * 2048;
    const float4* vnb = (const float4*)vn + half * 2048;
    float a0[16];
    #pragma unroll
    for (int bb = 0; bb < 16; ++bb) a0[bb] = 0.f;
    for (int it = 0; it < 8; ++it) {
        int idx = it * 256 + t;
        float4 w = rwr[idx];
        #pragma unroll
        for (int bb = 0; bb < 16; ++bb) {
            float4 vv = vnb[(size_t)bb * 4096 + idx];
            a0[bb] += w.x * vv.x + w.y * vv.y + w.z * vv.z + w.w * vv.w;
        }
    }
    #pragma unroll
    for (int off = 32; off >= 1; off >>= 1)
        #pragma unroll
        for (int bb = 0; bb < 16; ++bb)
            a0[bb] += __shfl_xor(a0[bb], off);
    const int wav = t >> 6, lane = t & 63;
    if (lane < 16) pr[wav][lane] = a0[lane];
    __syncthreads();
    if (t < 16)
        atomicAdd(&y[t * 512 + co], pr[0][t] + pr[1][t] + pr[2][t] + pr[3][t]);
}

// ---------------------------------------------------------------------------
// K2c: y = s/gnorm + rb, then BatchNorm1d (batch stats) + ReLU.
// ---------------------------------------------------------------------------
__global__ void k2c_bn(const float* __restrict__ y,
                       const float* __restrict__ gsq,
                       const float* __restrict__ rb,
                       const float* __restrict__ bnw,
                       const float* __restrict__ bnb,
                       float* __restrict__ out)
{
    const int co = threadIdx.x;
    const float rbv = rb[co];
    float vals[16];
    float m = 0.f;
    #pragma unroll
    for (int bb = 0; bb < 16; ++bb) {
        float gv = fmaxf(sqrtf(gsq[bb]), 1e-12f);
        vals[bb] = y[bb * 512 + co] / gv + rbv;
        m += vals[bb];
    }
    m *= (1.0f / 16.0f);
    float var = 0.f;
    #pragma unroll
    for (int bb = 0; bb < 16; ++bb) {
        float d = vals[bb] - m;
        var += d * d;
    }
    var *= (1.0f / 16.0f);
    float inv = 1.0f / sqrtf(var + 1e-5f);
    float w = bnw[co], bias = bnb[co];
    #pragma unroll
    for (int bb = 0; bb < 16; ++bb) {
        float o = w * (vals[bb] - m) * inv + bias;
        out[bb * 512 + co] = fmaxf(o, 0.f);
    }
}

// ---------------------------------------------------------------------------
extern "C" void kernel_launch(void* const* d_in, const int* in_sizes, int n_in,
                              void* d_out, int out_size, void* d_ws, size_t ws_size,
                              hipStream_t stream)
{
    const float* x    = (const float*)d_in[0];
    const float* aw   = (const float*)d_in[1];
    const float* ab   = (const float*)d_in[2];
    const float* cent = (const float*)d_in[3];
    const float* rw   = (const float*)d_in[4];
    const float* rb   = (const float*)d_in[5];
    const float* bnw  = (const float*)d_in[6];
    const float* bnb  = (const float*)d_in[7];
    float* out = (float*)d_out;

    char* ws = (char*)d_ws;
    float* agg  = (float*)(ws);                    // [0, 1 MB)
    float* asum = (float*)(ws + 0x100000);         // 4 KB
    float* gsq  = (float*)(ws + 0x101000);         // 64 B (padded)
    float* y    = (float*)(ws + 0x102000);         // 32 KB
    float* vn   = (float*)(ws + 0x110000);         // 1 MB

    hipMemsetAsync(ws, 0, 0x10A000, stream);       // zero agg+asum+gsq+y

    hipLaunchKernelGGL(k1_assign_agg, dim3(512), dim3(512), 0, stream,
                       x, aw, ab, agg, asum);
    hipLaunchKernelGGL(k2a_vlad_norm, dim3(B_ * K_), dim3(64), 0, stream,
                       agg, asum, cent, vn, gsq);
    hipLaunchKernelGGL(k2b_gemm, dim3(CO_ * 2), dim3(256), 0, stream,
                       vn, rw, y);
    hipLaunchKernelGGL(k2c_bn, dim3(1), dim3(512), 0, stream,
                       y, gsq, rb, bnw, bnb, out);
}